// Round 3
// baseline (222.790 us; speedup 1.0000x reference)
//
#include <hip/hip_runtime.h>
#include <stdint.h>

#define D_DIM 512
#define NSTEPS 10
#define ALPHA0 0.1f
#define DT_C 0.1f
#define BETA_C 2.8982753492378875f

typedef __attribute__((ext_vector_type(8))) short short8;
typedef __attribute__((ext_vector_type(4))) float floatx4;
typedef __attribute__((ext_vector_type(4))) unsigned short ushortx4;

__device__ __forceinline__ unsigned short f32_to_bf16(float f) {
    union { float f; uint32_t u; } v;
    v.f = f;
    uint32_t u = v.u;
    return (unsigned short)((u + 0x7FFFu + ((u >> 16) & 1u)) >> 16);
}
__device__ __forceinline__ float bf16_to_f32(unsigned short h) {
    union { uint32_t u; float f; } v;
    v.u = ((uint32_t)h) << 16;
    return v.f;
}

// ---------------------------------------------------------------------------
// Kernel 1: build L_rw in bf16 (row-major [e][d]). One wave per row.
// ---------------------------------------------------------------------------
__global__ __launch_bounds__(64) void prep_kernel(
    const float* __restrict__ W,
    unsigned short* __restrict__ Lbf)
{
    const int e = blockIdx.x;
    const int lane = threadIdx.x;
    const float* w = W + (size_t)e * D_DIM + lane * 8;
    const float4 v0 = *(const float4*)w;
    const float4 v1 = *(const float4*)(w + 4);
    float a[8] = { fabsf(v0.x), fabsf(v0.y), fabsf(v0.z), fabsf(v0.w),
                   fabsf(v1.x), fabsf(v1.y), fabsf(v1.z), fabsf(v1.w) };
    float s = a[0] + a[1] + a[2] + a[3] + a[4] + a[5] + a[6] + a[7];
#pragma unroll
    for (int off = 1; off < 64; off <<= 1) s += __shfl_xor(s, off, 64);
    const float inv = 1.0f / fmaxf(s, 1e-8f);
    short8 pk;
#pragma unroll
    for (int j = 0; j < 8; ++j) {
        const float diag = ((lane * 8 + j) == e) ? 1.0f : 0.0f;
        pk[j] = (short)f32_to_bf16(diag - a[j] * inv);
    }
    *(short8*)(Lbf + (size_t)e * D_DIM + lane * 8) = pk;
}

// ---------------------------------------------------------------------------
// Kernel 2: full 10-step settle on operator columns + G build, ONE launch.
// Block b owns operator columns c in [16b,16b+16) — fully independent rows.
// 4 waves; wave w owns e in [128w,128w+128) (8 m-frags). State in registers
// (MFMA C-layout): At[m][j], Bt[m][j] at (e = ebase+16m+4q+j, c = cbase+lrow).
// Per step: coupling[e][c] = sum_d L[e][d]*Abf[c][d] via MFMA
//   (A-op = Lbf row-major [e][d] from L2, B-op = Abf row-major [c][d] in LDS).
// Epilogue: Gbf[e][c] = g*A10[e][c] (off-diag), Gdiag[e] = (1-g)+g*A10[e][e].
// ---------------------------------------------------------------------------
__global__ __launch_bounds__(256, 1) void chain_kernel(
    const unsigned short* __restrict__ Lbf,   // [e][d]
    const float* __restrict__ prec,
    const float* __restrict__ gate_alpha,
    unsigned short* __restrict__ Gbf,         // [e][d]
    float* __restrict__ Gdiag)
{
    const int tid = threadIdx.x;
    const int wave = tid >> 6, lane = tid & 63;
    const int lrow = lane & 15, q = lane >> 4;
    const int cbase = blockIdx.x * 16;
    const int c_glob = cbase + lrow;
    const int ebase = wave * 128;

    __shared__ unsigned short Abf[16 * D_DIM];   // [c_local][d], swizzled

    // preload prec for this lane's e set
    float pr[8][4];
#pragma unroll
    for (int m = 0; m < 8; ++m)
#pragma unroll
        for (int j = 0; j < 4; ++j)
            pr[m][j] = prec[ebase + m * 16 + q * 4 + j];

    // state init: At = I, Bt = 0
    floatx4 At[8], Bt[8];
#pragma unroll
    for (int m = 0; m < 8; ++m) {
#pragma unroll
        for (int j = 0; j < 4; ++j) {
            const int e = ebase + m * 16 + q * 4 + j;
            At[m][j] = (e == c_glob) ? 1.0f : 0.0f;
            Bt[m][j] = 0.0f;
        }
    }

    // write Abf chunk for this lane: row c_local=lrow, cols e..e+3 (8 bytes)
    char* lds = (char*)Abf;
#pragma unroll
    for (int m = 0; m < 8; ++m) {
        ushortx4 pk;
#pragma unroll
        for (int j = 0; j < 4; ++j) pk[j] = f32_to_bf16(At[m][j]);
        int byte = lrow * (D_DIM * 2) + (ebase + m * 16 + q * 4) * 2;
        byte ^= (lrow & 7) << 4;
        *(ushortx4*)(lds + byte) = pk;
    }
    __syncthreads();

    for (int step = 0; step < NSTEPS; ++step) {
        floatx4 acc[8] = {};
#pragma unroll 4
        for (int kk = 0; kk < 16; ++kk) {
            int bbyte = lrow * (D_DIM * 2) + (kk * 32 + q * 8) * 2;
            bbyte ^= (lrow & 7) << 4;
            const short8 b = *(const short8*)(lds + bbyte);
#pragma unroll
            for (int m = 0; m < 8; ++m) {
                const short8 a = *(const short8*)(
                    Lbf + (size_t)(ebase + m * 16 + lrow) * D_DIM + kk * 32 + q * 8);
                acc[m] = __builtin_amdgcn_mfma_f32_16x16x32_bf16(a, b, acc[m], 0, 0, 0);
            }
        }
        // state update (exact f32 for diagonal terms)
#pragma unroll
        for (int m = 0; m < 8; ++m) {
#pragma unroll
            for (int j = 0; j < 4; ++j) {
                const int e = ebase + m * 16 + q * 4 + j;
                const float p = pr[m][j];
                const float tgt = (e == c_glob) ? p : 0.0f;
                const float force = -acc[m][j] - (ALPHA0 + p) * At[m][j]
                                    + tgt - BETA_C * Bt[m][j];
                Bt[m][j] += DT_C * force;
                At[m][j] += DT_C * Bt[m][j];
            }
        }
        if (step < NSTEPS - 1) {
            __syncthreads();   // all waves done reading Abf
#pragma unroll
            for (int m = 0; m < 8; ++m) {
                ushortx4 pk;
#pragma unroll
                for (int j = 0; j < 4; ++j) pk[j] = f32_to_bf16(At[m][j]);
                int byte = lrow * (D_DIM * 2) + (ebase + m * 16 + q * 4) * 2;
                byte ^= (lrow & 7) << 4;
                *(ushortx4*)(lds + byte) = pk;
            }
            __syncthreads();
        }
    }

    // epilogue: G build
    const float g = tanhf(gate_alpha[0]);
#pragma unroll
    for (int m = 0; m < 8; ++m) {
#pragma unroll
        for (int j = 0; j < 4; ++j) {
            const int e = ebase + m * 16 + q * 4 + j;
            const size_t idx = (size_t)e * D_DIM + c_glob;
            if (e == c_glob) {
                Gdiag[e] = (1.0f - g) + g * At[m][j];
                Gbf[idx] = 0;
            } else {
                Gbf[idx] = f32_to_bf16(g * At[m][j]);
            }
        }
    }
}

// ---------------------------------------------------------------------------
// Kernel 3: out = H @ G^T + diag part.
// Tile 32 rows x 512 cols, 512 blocks, 4 waves; wave w owns cols [128w,128w+128).
// H tile staged bf16 in swizzled LDS; epilogue diag term from LDS (bf16 h).
// ---------------------------------------------------------------------------
__global__ __launch_bounds__(256) void out_gemm(
    const float* __restrict__ H,              // [16384][512]
    const unsigned short* __restrict__ Gbf,   // [e][d]
    const float* __restrict__ Gdiag,
    float* __restrict__ Out)
{
    const int r0 = blockIdx.x * 32;
    const int tid = threadIdx.x;
    const int wave = tid >> 6, lane = tid & 63;
    const int lrow = lane & 15, q = lane >> 4;

    __shared__ unsigned short hlds[32 * D_DIM];  // 32 KiB, swizzled
    char* lds = (char*)hlds;

    // stage: wave w loads rows [8w, 8w+8); lane covers cols [8*lane, 8*lane+8)
#pragma unroll
    for (int i = 0; i < 8; ++i) {
        const int row = wave * 8 + i;
        const float* src = H + (size_t)(r0 + row) * D_DIM + lane * 8;
        const float4 v0 = *(const float4*)src;
        const float4 v1 = *(const float4*)(src + 4);
        short8 pk;
        pk[0] = (short)f32_to_bf16(v0.x); pk[1] = (short)f32_to_bf16(v0.y);
        pk[2] = (short)f32_to_bf16(v0.z); pk[3] = (short)f32_to_bf16(v0.w);
        pk[4] = (short)f32_to_bf16(v1.x); pk[5] = (short)f32_to_bf16(v1.y);
        pk[6] = (short)f32_to_bf16(v1.z); pk[7] = (short)f32_to_bf16(v1.w);
        int byte = row * (D_DIM * 2) + lane * 16;
        byte ^= (row & 7) << 4;
        *(short8*)(lds + byte) = pk;
    }
    __syncthreads();

    float gd[8];
#pragma unroll
    for (int n = 0; n < 8; ++n) gd[n] = Gdiag[wave * 128 + n * 16 + lrow];

    floatx4 acc[2][8] = {};
#pragma unroll 4
    for (int kk = 0; kk < 16; ++kk) {
        short8 a[2];
#pragma unroll
        for (int m = 0; m < 2; ++m) {
            const int row = m * 16 + lrow;
            int byte = row * (D_DIM * 2) + (kk * 32 + q * 8) * 2;
            byte ^= (row & 7) << 4;
            a[m] = *(const short8*)(lds + byte);
        }
#pragma unroll
        for (int n = 0; n < 8; ++n) {
            const short8 b = *(const short8*)(
                Gbf + (size_t)(wave * 128 + n * 16 + lrow) * D_DIM + kk * 32 + q * 8);
#pragma unroll
            for (int m = 0; m < 2; ++m)
                acc[m][n] = __builtin_amdgcn_mfma_f32_16x16x32_bf16(a[m], b, acc[m][n], 0, 0, 0);
        }
    }

    // epilogue: Out[r][e] = acc + h_bf16[r][e] * Gdiag[e]
#pragma unroll
    for (int m = 0; m < 2; ++m) {
#pragma unroll
        for (int j = 0; j < 4; ++j) {
            const int r_loc = m * 16 + q * 4 + j;
#pragma unroll
            for (int n = 0; n < 8; ++n) {
                const int e = wave * 128 + n * 16 + lrow;
                int byte = r_loc * (D_DIM * 2) + e * 2;
                byte ^= (r_loc & 7) << 4;
                const float h = bf16_to_f32(*(const unsigned short*)(lds + byte));
                Out[(size_t)(r0 + r_loc) * D_DIM + e] = acc[m][n][j] + h * gd[n];
            }
        }
    }
}

// ---------------------------------------------------------------------------
extern "C" void kernel_launch(void* const* d_in, const int* in_sizes, int n_in,
                              void* d_out, int out_size, void* d_ws, size_t ws_size,
                              hipStream_t stream)
{
    const float* H    = (const float*)d_in[0];   // (4,4096,512)
    const float* W    = (const float*)d_in[1];   // (512,512)
    const float* gate = (const float*)d_in[2];   // (1,)
    const float* prec = (const float*)d_in[3];   // (512,)
    float* out = (float*)d_out;
    char* ws = (char*)d_ws;

    unsigned short* Lbf   = (unsigned short*)(ws);                 // 512 KiB
    unsigned short* Gbf   = (unsigned short*)(ws + (512u << 10));  // 512 KiB
    float*          Gdiag = (float*)(ws + (1024u << 10));          // 2 KiB

    prep_kernel<<<dim3(D_DIM), dim3(64), 0, stream>>>(W, Lbf);

    chain_kernel<<<dim3(D_DIM / 16), dim3(256), 0, stream>>>(
        Lbf, prec, gate, Gbf, Gdiag);

    out_gemm<<<dim3(16384 / 32), dim3(256), 0, stream>>>(H, Gbf, Gdiag, out);
}

// Round 4
// 161.298 us; speedup vs baseline: 1.3812x; 1.3812x over previous
//
#include <hip/hip_runtime.h>
#include <stdint.h>

#define D_DIM 512
#define NSTEPS 10
#define ALPHA0 0.1f
#define DT_C 0.1f
#define BETA_C 2.8982753492378875f

typedef __attribute__((ext_vector_type(8))) short short8;
typedef __attribute__((ext_vector_type(4))) float floatx4;
typedef __attribute__((ext_vector_type(4))) unsigned short ushortx4;

__device__ __forceinline__ unsigned short f32_to_bf16(float f) {
    union { float f; uint32_t u; } v;
    v.f = f;
    uint32_t u = v.u;
    return (unsigned short)((u + 0x7FFFu + ((u >> 16) & 1u)) >> 16);
}
__device__ __forceinline__ float bf16_to_f32(unsigned short h) {
    union { uint32_t u; float f; } v;
    v.u = ((uint32_t)h) << 16;
    return v.f;
}

// ---------------------------------------------------------------------------
// Kernel 1: build L_rw in bf16 (row-major [e][d]). One wave per row.
// ---------------------------------------------------------------------------
__global__ __launch_bounds__(64) void prep_kernel(
    const float* __restrict__ W,
    unsigned short* __restrict__ Lbf)
{
    const int e = blockIdx.x;
    const int lane = threadIdx.x;
    const float* w = W + (size_t)e * D_DIM + lane * 8;
    const float4 v0 = *(const float4*)w;
    const float4 v1 = *(const float4*)(w + 4);
    float a[8] = { fabsf(v0.x), fabsf(v0.y), fabsf(v0.z), fabsf(v0.w),
                   fabsf(v1.x), fabsf(v1.y), fabsf(v1.z), fabsf(v1.w) };
    float s = a[0] + a[1] + a[2] + a[3] + a[4] + a[5] + a[6] + a[7];
#pragma unroll
    for (int off = 1; off < 64; off <<= 1) s += __shfl_xor(s, off, 64);
    const float inv = 1.0f / fmaxf(s, 1e-8f);
    short8 pk;
#pragma unroll
    for (int j = 0; j < 8; ++j) {
        const float diag = ((lane * 8 + j) == e) ? 1.0f : 0.0f;
        pk[j] = (short)f32_to_bf16(diag - a[j] * inv);
    }
    *(short8*)(Lbf + (size_t)e * D_DIM + lane * 8) = pk;
}

// ---------------------------------------------------------------------------
// Kernel 2: full 10-step settle, ONE launch, 32 blocks x 1024 threads.
// Block b owns operator columns c in [16b,16b+16). 16 waves; wave w owns
// e in [32w, 32w+32) (2 m-frags) -> 4 waves/SIMD for latency hiding.
// State in registers (MFMA C-layout). A (bf16, [c][d]) double-buffered in LDS,
// ONE barrier per step. L read from L2 (resident after step 0), 2 batched
// 16B loads per kk.
// ---------------------------------------------------------------------------
__global__ __launch_bounds__(1024) void chain_kernel(
    const unsigned short* __restrict__ Lbf,   // [e][d]
    const float* __restrict__ prec,
    const float* __restrict__ gate_alpha,
    unsigned short* __restrict__ Gbf,         // [e][d]
    float* __restrict__ Gdiag)
{
    const int tid = threadIdx.x;
    const int wave = tid >> 6, lane = tid & 63;
    const int lrow = lane & 15, q = lane >> 4;
    const int c_glob = blockIdx.x * 16 + lrow;
    const int ebase = wave * 32;

    __shared__ unsigned short Abuf[2][16 * D_DIM];   // 2 x 16 KiB, swizzled
    char* lds0 = (char*)Abuf[0];
    char* lds1 = (char*)Abuf[1];

    float pr[2][4];
#pragma unroll
    for (int m = 0; m < 2; ++m)
#pragma unroll
        for (int j = 0; j < 4; ++j)
            pr[m][j] = prec[ebase + m * 16 + q * 4 + j];

    floatx4 At[2], Bt[2];
#pragma unroll
    for (int m = 0; m < 2; ++m) {
#pragma unroll
        for (int j = 0; j < 4; ++j) {
            const int e = ebase + m * 16 + q * 4 + j;
            At[m][j] = (e == c_glob) ? 1.0f : 0.0f;
            Bt[m][j] = 0.0f;
        }
    }

    // init buffer 0 with A0 = I
#pragma unroll
    for (int m = 0; m < 2; ++m) {
        ushortx4 pk;
#pragma unroll
        for (int j = 0; j < 4; ++j) pk[j] = f32_to_bf16(At[m][j]);
        int byte = lrow * (D_DIM * 2) + (ebase + m * 16 + q * 4) * 2;
        byte ^= (lrow & 7) << 4;
        *(ushortx4*)(lds0 + byte) = pk;
    }
    __syncthreads();

    const short8* Lr0 = (const short8*)(Lbf + (size_t)(ebase + lrow) * D_DIM);
    const short8* Lr1 = (const short8*)(Lbf + (size_t)(ebase + 16 + lrow) * D_DIM);

    for (int step = 0; step < NSTEPS; ++step) {
        char* src = (step & 1) ? lds1 : lds0;
        floatx4 acc[2] = {};
#pragma unroll
        for (int kk = 0; kk < 16; ++kk) {
            int bbyte = lrow * (D_DIM * 2) + (kk * 32 + q * 8) * 2;
            bbyte ^= (lrow & 7) << 4;
            const short8 b  = *(const short8*)(src + bbyte);
            const short8 a0 = Lr0[kk * 4 + q];
            const short8 a1 = Lr1[kk * 4 + q];
            acc[0] = __builtin_amdgcn_mfma_f32_16x16x32_bf16(a0, b, acc[0], 0, 0, 0);
            acc[1] = __builtin_amdgcn_mfma_f32_16x16x32_bf16(a1, b, acc[1], 0, 0, 0);
        }
        // state update (f32)
#pragma unroll
        for (int m = 0; m < 2; ++m) {
#pragma unroll
            for (int j = 0; j < 4; ++j) {
                const int e = ebase + m * 16 + q * 4 + j;
                const float p = pr[m][j];
                const float tgt = (e == c_glob) ? p : 0.0f;
                const float force = -acc[m][j] - (ALPHA0 + p) * At[m][j]
                                    + tgt - BETA_C * Bt[m][j];
                Bt[m][j] += DT_C * force;
                At[m][j] += DT_C * Bt[m][j];
            }
        }
        if (step < NSTEPS - 1) {
            char* dst = (step & 1) ? lds0 : lds1;
#pragma unroll
            for (int m = 0; m < 2; ++m) {
                ushortx4 pk;
#pragma unroll
                for (int j = 0; j < 4; ++j) pk[j] = f32_to_bf16(At[m][j]);
                int byte = lrow * (D_DIM * 2) + (ebase + m * 16 + q * 4) * 2;
                byte ^= (lrow & 7) << 4;
                *(ushortx4*)(dst + byte) = pk;
            }
            __syncthreads();
        }
    }

    // epilogue: G build
    const float g = tanhf(gate_alpha[0]);
#pragma unroll
    for (int m = 0; m < 2; ++m) {
#pragma unroll
        for (int j = 0; j < 4; ++j) {
            const int e = ebase + m * 16 + q * 4 + j;
            const size_t idx = (size_t)e * D_DIM + c_glob;
            if (e == c_glob) {
                Gdiag[e] = (1.0f - g) + g * At[m][j];
                Gbf[idx] = 0;
            } else {
                Gbf[idx] = f32_to_bf16(g * At[m][j]);
            }
        }
    }
}

// ---------------------------------------------------------------------------
// Kernel 3: out = H @ G^T + diag part.
// Tile 32 rows x 512 cols, 512 blocks, 4 waves; wave w owns cols [128w,128w+128).
// H staged bf16 in swizzled LDS; all 8 Gbf b-frags batched per kk before MFMAs.
// ---------------------------------------------------------------------------
__global__ __launch_bounds__(256) void out_gemm(
    const float* __restrict__ H,              // [16384][512]
    const unsigned short* __restrict__ Gbf,   // [e][d]
    const float* __restrict__ Gdiag,
    float* __restrict__ Out)
{
    const int r0 = blockIdx.x * 32;
    const int tid = threadIdx.x;
    const int wave = tid >> 6, lane = tid & 63;
    const int lrow = lane & 15, q = lane >> 4;

    __shared__ unsigned short hlds[32 * D_DIM];  // 32 KiB, swizzled
    char* lds = (char*)hlds;

    // stage: wave w loads rows [8w, 8w+8); lane covers cols [8*lane, 8*lane+8)
#pragma unroll
    for (int i = 0; i < 8; ++i) {
        const int row = wave * 8 + i;
        const float* src = H + (size_t)(r0 + row) * D_DIM + lane * 8;
        const float4 v0 = *(const float4*)src;
        const float4 v1 = *(const float4*)(src + 4);
        short8 pk;
        pk[0] = (short)f32_to_bf16(v0.x); pk[1] = (short)f32_to_bf16(v0.y);
        pk[2] = (short)f32_to_bf16(v0.z); pk[3] = (short)f32_to_bf16(v0.w);
        pk[4] = (short)f32_to_bf16(v1.x); pk[5] = (short)f32_to_bf16(v1.y);
        pk[6] = (short)f32_to_bf16(v1.z); pk[7] = (short)f32_to_bf16(v1.w);
        int byte = row * (D_DIM * 2) + lane * 16;
        byte ^= (row & 7) << 4;
        *(short8*)(lds + byte) = pk;
    }
    __syncthreads();

    float gd[8];
#pragma unroll
    for (int n = 0; n < 8; ++n) gd[n] = Gdiag[wave * 128 + n * 16 + lrow];

    const unsigned short* gbase = Gbf + (size_t)(wave * 128 + lrow) * D_DIM + q * 8;

    floatx4 acc[2][8] = {};
#pragma unroll 2
    for (int kk = 0; kk < 16; ++kk) {
        short8 b[8];
#pragma unroll
        for (int n = 0; n < 8; ++n)
            b[n] = *(const short8*)(gbase + (size_t)n * 16 * D_DIM + kk * 32);
        short8 a[2];
#pragma unroll
        for (int m = 0; m < 2; ++m) {
            const int row = m * 16 + lrow;
            int byte = row * (D_DIM * 2) + (kk * 32 + q * 8) * 2;
            byte ^= (row & 7) << 4;
            a[m] = *(const short8*)(lds + byte);
        }
#pragma unroll
        for (int n = 0; n < 8; ++n)
#pragma unroll
            for (int m = 0; m < 2; ++m)
                acc[m][n] = __builtin_amdgcn_mfma_f32_16x16x32_bf16(a[m], b[n], acc[m][n], 0, 0, 0);
    }

    // epilogue: Out[r][e] = acc + h_bf16[r][e] * Gdiag[e]
#pragma unroll
    for (int m = 0; m < 2; ++m) {
#pragma unroll
        for (int j = 0; j < 4; ++j) {
            const int r_loc = m * 16 + q * 4 + j;
#pragma unroll
            for (int n = 0; n < 8; ++n) {
                const int e = wave * 128 + n * 16 + lrow;
                int byte = r_loc * (D_DIM * 2) + e * 2;
                byte ^= (r_loc & 7) << 4;
                const float h = bf16_to_f32(*(const unsigned short*)(lds + byte));
                Out[(size_t)(r0 + r_loc) * D_DIM + e] = acc[m][n][j] + h * gd[n];
            }
        }
    }
}

// ---------------------------------------------------------------------------
extern "C" void kernel_launch(void* const* d_in, const int* in_sizes, int n_in,
                              void* d_out, int out_size, void* d_ws, size_t ws_size,
                              hipStream_t stream)
{
    const float* H    = (const float*)d_in[0];   // (4,4096,512)
    const float* W    = (const float*)d_in[1];   // (512,512)
    const float* gate = (const float*)d_in[2];   // (1,)
    const float* prec = (const float*)d_in[3];   // (512,)
    float* out = (float*)d_out;
    char* ws = (char*)d_ws;

    unsigned short* Lbf   = (unsigned short*)(ws);                 // 512 KiB
    unsigned short* Gbf   = (unsigned short*)(ws + (512u << 10));  // 512 KiB
    float*          Gdiag = (float*)(ws + (1024u << 10));          // 2 KiB

    prep_kernel<<<dim3(D_DIM), dim3(64), 0, stream>>>(W, Lbf);

    chain_kernel<<<dim3(D_DIM / 16), dim3(1024), 0, stream>>>(
        Lbf, prec, gate, Gbf, Gdiag);

    out_gemm<<<dim3(16384 / 32), dim3(256), 0, stream>>>(H, Gbf, Gdiag, out);
}

// Round 5
// 147.472 us; speedup vs baseline: 1.5107x; 1.0938x over previous
//
#include <hip/hip_runtime.h>
#include <stdint.h>

#define D_DIM 512
#define NSTEPS 10
#define ALPHA0 0.1f
#define DT_C 0.1f
#define BETA_C 2.8982753492378875f

typedef __attribute__((ext_vector_type(8))) short short8;
typedef __attribute__((ext_vector_type(4))) float floatx4;
typedef __attribute__((ext_vector_type(4))) unsigned short ushortx4;

__device__ __forceinline__ unsigned short f32_to_bf16(float f) {
    union { float f; uint32_t u; } v;
    v.f = f;
    uint32_t u = v.u;
    return (unsigned short)((u + 0x7FFFu + ((u >> 16) & 1u)) >> 16);
}
__device__ __forceinline__ float bf16_to_f32(unsigned short h) {
    union { uint32_t u; float f; } v;
    v.u = ((uint32_t)h) << 16;
    return v.f;
}

// ---------------------------------------------------------------------------
// Kernel 1: build L_rw in bf16 (row-major [e][d]). One wave per row.
// ---------------------------------------------------------------------------
__global__ __launch_bounds__(64) void prep_kernel(
    const float* __restrict__ W,
    unsigned short* __restrict__ Lbf)
{
    const int e = blockIdx.x;
    const int lane = threadIdx.x;
    const float* w = W + (size_t)e * D_DIM + lane * 8;
    const float4 v0 = *(const float4*)w;
    const float4 v1 = *(const float4*)(w + 4);
    float a[8] = { fabsf(v0.x), fabsf(v0.y), fabsf(v0.z), fabsf(v0.w),
                   fabsf(v1.x), fabsf(v1.y), fabsf(v1.z), fabsf(v1.w) };
    float s = a[0] + a[1] + a[2] + a[3] + a[4] + a[5] + a[6] + a[7];
#pragma unroll
    for (int off = 1; off < 64; off <<= 1) s += __shfl_xor(s, off, 64);
    const float inv = 1.0f / fmaxf(s, 1e-8f);
    short8 pk;
#pragma unroll
    for (int j = 0; j < 8; ++j) {
        const float diag = ((lane * 8 + j) == e) ? 1.0f : 0.0f;
        pk[j] = (short)f32_to_bf16(diag - a[j] * inv);
    }
    *(short8*)(Lbf + (size_t)e * D_DIM + lane * 8) = pk;
}

// ---------------------------------------------------------------------------
// Kernel 2: full 10-step settle + G build, ONE launch, 32 blocks x 1024 thr.
// Block owns 16 c-columns; wave w owns e-rows [32w, 32w+32) (2 m-frags).
// L persistence per wave:
//   m0 frags (rows [32w,32w+16), all 16 kk) : 64 VGPRs        (Mreg)
//   m1 frags kk=0..6                        : 112 KB LDS total (M1l)
//   m1 frags kk=7..15                       : streamed from L2, 4-deep ring
// A (bf16, [c][d] swizzled) double-buffered in LDS (32 KB), 1 barrier/step.
// ---------------------------------------------------------------------------
__global__ __launch_bounds__(1024) void chain_kernel(
    const unsigned short* __restrict__ Lbf,   // [e][d]
    const float* __restrict__ prec,
    const float* __restrict__ gate_alpha,
    unsigned short* __restrict__ Gbf,         // [e][d]
    float* __restrict__ Gdiag)
{
    const int tid = threadIdx.x;
    const int wave = tid >> 6, lane = tid & 63;
    const int lrow = lane & 15, q = lane >> 4;
    const int c_glob = blockIdx.x * 16 + lrow;
    const int ebase = wave * 32;

    __shared__ unsigned short Abuf[2][16 * D_DIM];   // 2 x 16 KiB, swizzled
    __shared__ unsigned short M1l[16 * 7 * 512];     // 112 KiB: per-wave m1 frags kk=0..6
    char* lds0 = (char*)Abuf[0];
    char* lds1 = (char*)Abuf[1];

    const short8* L0 = (const short8*)(Lbf + (size_t)(ebase + lrow) * D_DIM);
    const short8* L1 = (const short8*)(Lbf + (size_t)(ebase + 16 + lrow) * D_DIM);

    // persist m0 frags in registers (64 VGPRs)
    short8 Mreg[16];
#pragma unroll
    for (int kk = 0; kk < 16; ++kk) Mreg[kk] = L0[kk * 4 + q];

    // persist m1 frags kk=0..6 in LDS (own region per wave, no barrier needed)
#pragma unroll
    for (int k7 = 0; k7 < 7; ++k7) {
        short8 v = L1[k7 * 4 + q];
        *(short8*)(M1l + (size_t)(wave * 7 + k7) * 512 + lane * 8) = v;
    }

    float pr[2][4];
#pragma unroll
    for (int m = 0; m < 2; ++m)
#pragma unroll
        for (int j = 0; j < 4; ++j)
            pr[m][j] = prec[ebase + m * 16 + q * 4 + j];

    floatx4 At[2], Bt[2];
#pragma unroll
    for (int m = 0; m < 2; ++m) {
#pragma unroll
        for (int j = 0; j < 4; ++j) {
            const int e = ebase + m * 16 + q * 4 + j;
            At[m][j] = (e == c_glob) ? 1.0f : 0.0f;
            Bt[m][j] = 0.0f;
        }
    }

    // init buffer 0 with A0 = I
#pragma unroll
    for (int m = 0; m < 2; ++m) {
        ushortx4 pk;
#pragma unroll
        for (int j = 0; j < 4; ++j) pk[j] = f32_to_bf16(At[m][j]);
        int byte = lrow * (D_DIM * 2) + (ebase + m * 16 + q * 4) * 2;
        byte ^= (lrow & 7) << 4;
        *(ushortx4*)(lds0 + byte) = pk;
    }
    __syncthreads();

    for (int step = 0; step < NSTEPS; ++step) {
        char* src = (step & 1) ? lds1 : lds0;
        // prime 4-deep prefetch ring with streamed frags 7..10
        short8 pf[4];
#pragma unroll
        for (int i = 0; i < 4; ++i) pf[i] = L1[(7 + i) * 4 + q];

        floatx4 acc[2] = {};
#pragma unroll
        for (int kk = 0; kk < 16; ++kk) {
            int bbyte = lrow * (D_DIM * 2) + (kk * 32 + q * 8) * 2;
            bbyte ^= (lrow & 7) << 4;
            const short8 b = *(const short8*)(src + bbyte);
            short8 a1;
            if (kk < 7) {
                a1 = *(const short8*)(M1l + (size_t)(wave * 7 + kk) * 512 + lane * 8);
            } else {
                a1 = pf[(kk - 7) & 3];
                if (kk + 4 < 16) pf[(kk - 7) & 3] = L1[(kk + 4) * 4 + q];
            }
            acc[0] = __builtin_amdgcn_mfma_f32_16x16x32_bf16(Mreg[kk], b, acc[0], 0, 0, 0);
            acc[1] = __builtin_amdgcn_mfma_f32_16x16x32_bf16(a1, b, acc[1], 0, 0, 0);
        }
        // state update (f32)
#pragma unroll
        for (int m = 0; m < 2; ++m) {
#pragma unroll
            for (int j = 0; j < 4; ++j) {
                const int e = ebase + m * 16 + q * 4 + j;
                const float p = pr[m][j];
                const float tgt = (e == c_glob) ? p : 0.0f;
                const float force = -acc[m][j] - (ALPHA0 + p) * At[m][j]
                                    + tgt - BETA_C * Bt[m][j];
                Bt[m][j] += DT_C * force;
                At[m][j] += DT_C * Bt[m][j];
            }
        }
        if (step < NSTEPS - 1) {
            char* dst = (step & 1) ? lds0 : lds1;
#pragma unroll
            for (int m = 0; m < 2; ++m) {
                ushortx4 pk;
#pragma unroll
                for (int j = 0; j < 4; ++j) pk[j] = f32_to_bf16(At[m][j]);
                int byte = lrow * (D_DIM * 2) + (ebase + m * 16 + q * 4) * 2;
                byte ^= (lrow & 7) << 4;
                *(ushortx4*)(dst + byte) = pk;
            }
            __syncthreads();
        }
    }

    // epilogue: G build
    const float g = tanhf(gate_alpha[0]);
#pragma unroll
    for (int m = 0; m < 2; ++m) {
#pragma unroll
        for (int j = 0; j < 4; ++j) {
            const int e = ebase + m * 16 + q * 4 + j;
            const size_t idx = (size_t)e * D_DIM + c_glob;
            if (e == c_glob) {
                Gdiag[e] = (1.0f - g) + g * At[m][j];
                Gbf[idx] = 0;
            } else {
                Gbf[idx] = f32_to_bf16(g * At[m][j]);
            }
        }
    }
}

// ---------------------------------------------------------------------------
// Kernel 3: out = H @ G^T + diag part.
// Tile 32 rows x 512 cols, 512 blocks, 4 waves; wave w owns cols [128w,+128).
// H staged bf16 in swizzled LDS; Gbf b-frags ping-pong prefetched (b0/b1)
// so the 8 L2 loads of kk+1 overlap the 16 MFMAs of kk.
// ---------------------------------------------------------------------------
__global__ __launch_bounds__(256) void out_gemm(
    const float* __restrict__ H,              // [16384][512]
    const unsigned short* __restrict__ Gbf,   // [e][d]
    const float* __restrict__ Gdiag,
    float* __restrict__ Out)
{
    const int r0 = blockIdx.x * 32;
    const int tid = threadIdx.x;
    const int wave = tid >> 6, lane = tid & 63;
    const int lrow = lane & 15, q = lane >> 4;

    __shared__ unsigned short hlds[32 * D_DIM];  // 32 KiB, swizzled
    char* lds = (char*)hlds;

    const unsigned short* gbase = Gbf + (size_t)(wave * 128 + lrow) * D_DIM + q * 8;

    // issue first b-frag batch before the barrier (independent of LDS)
    short8 b0[8], b1[8];
#pragma unroll
    for (int n = 0; n < 8; ++n)
        b0[n] = *(const short8*)(gbase + (size_t)n * 16 * D_DIM);

    // stage: wave w loads rows [8w, 8w+8); lane covers cols [8*lane, 8*lane+8)
#pragma unroll
    for (int i = 0; i < 8; ++i) {
        const int row = wave * 8 + i;
        const float* src = H + (size_t)(r0 + row) * D_DIM + lane * 8;
        const float4 v0 = *(const float4*)src;
        const float4 v1 = *(const float4*)(src + 4);
        short8 pk;
        pk[0] = (short)f32_to_bf16(v0.x); pk[1] = (short)f32_to_bf16(v0.y);
        pk[2] = (short)f32_to_bf16(v0.z); pk[3] = (short)f32_to_bf16(v0.w);
        pk[4] = (short)f32_to_bf16(v1.x); pk[5] = (short)f32_to_bf16(v1.y);
        pk[6] = (short)f32_to_bf16(v1.z); pk[7] = (short)f32_to_bf16(v1.w);
        int byte = row * (D_DIM * 2) + lane * 16;
        byte ^= (row & 7) << 4;
        *(short8*)(lds + byte) = pk;
    }
    __syncthreads();

    float gd[8];
#pragma unroll
    for (int n = 0; n < 8; ++n) gd[n] = Gdiag[wave * 128 + n * 16 + lrow];

    floatx4 acc[2][8] = {};
#pragma unroll
    for (int k2 = 0; k2 < 16; k2 += 2) {
        // prefetch odd kk into b1
#pragma unroll
        for (int n = 0; n < 8; ++n)
            b1[n] = *(const short8*)(gbase + (size_t)n * 16 * D_DIM + (k2 + 1) * 32);
        {
            short8 a[2];
#pragma unroll
            for (int m = 0; m < 2; ++m) {
                const int row = m * 16 + lrow;
                int byte = row * (D_DIM * 2) + (k2 * 32 + q * 8) * 2;
                byte ^= (row & 7) << 4;
                a[m] = *(const short8*)(lds + byte);
            }
#pragma unroll
            for (int n = 0; n < 8; ++n)
#pragma unroll
                for (int m = 0; m < 2; ++m)
                    acc[m][n] = __builtin_amdgcn_mfma_f32_16x16x32_bf16(a[m], b0[n], acc[m][n], 0, 0, 0);
        }
        // prefetch next even kk into b0
        if (k2 + 2 < 16) {
#pragma unroll
            for (int n = 0; n < 8; ++n)
                b0[n] = *(const short8*)(gbase + (size_t)n * 16 * D_DIM + (k2 + 2) * 32);
        }
        {
            short8 a[2];
#pragma unroll
            for (int m = 0; m < 2; ++m) {
                const int row = m * 16 + lrow;
                int byte = row * (D_DIM * 2) + ((k2 + 1) * 32 + q * 8) * 2;
                byte ^= (row & 7) << 4;
                a[m] = *(const short8*)(lds + byte);
            }
#pragma unroll
            for (int n = 0; n < 8; ++n)
#pragma unroll
                for (int m = 0; m < 2; ++m)
                    acc[m][n] = __builtin_amdgcn_mfma_f32_16x16x32_bf16(a[m], b1[n], acc[m][n], 0, 0, 0);
        }
    }

    // epilogue: Out[r][e] = acc + h_bf16[r][e] * Gdiag[e]
#pragma unroll
    for (int m = 0; m < 2; ++m) {
#pragma unroll
        for (int j = 0; j < 4; ++j) {
            const int r_loc = m * 16 + q * 4 + j;
#pragma unroll
            for (int n = 0; n < 8; ++n) {
                const int e = wave * 128 + n * 16 + lrow;
                int byte = r_loc * (D_DIM * 2) + e * 2;
                byte ^= (r_loc & 7) << 4;
                const float h = bf16_to_f32(*(const unsigned short*)(lds + byte));
                Out[(size_t)(r0 + r_loc) * D_DIM + e] = acc[m][n][j] + h * gd[n];
            }
        }
    }
}

// ---------------------------------------------------------------------------
extern "C" void kernel_launch(void* const* d_in, const int* in_sizes, int n_in,
                              void* d_out, int out_size, void* d_ws, size_t ws_size,
                              hipStream_t stream)
{
    const float* H    = (const float*)d_in[0];   // (4,4096,512)
    const float* W    = (const float*)d_in[1];   // (512,512)
    const float* gate = (const float*)d_in[2];   // (1,)
    const float* prec = (const float*)d_in[3];   // (512,)
    float* out = (float*)d_out;
    char* ws = (char*)d_ws;

    unsigned short* Lbf   = (unsigned short*)(ws);                 // 512 KiB
    unsigned short* Gbf   = (unsigned short*)(ws + (512u << 10));  // 512 KiB
    float*          Gdiag = (float*)(ws + (1024u << 10));          // 2 KiB

    prep_kernel<<<dim3(D_DIM), dim3(64), 0, stream>>>(W, Lbf);

    chain_kernel<<<dim3(D_DIM / 16), dim3(1024), 0, stream>>>(
        Lbf, prec, gate, Gbf, Gdiag);

    out_gemm<<<dim3(16384 / 32), dim3(256), 0, stream>>>(H, Gbf, Gdiag, out);
}

// Round 7
// 135.817 us; speedup vs baseline: 1.6404x; 1.0858x over previous
//
#include <hip/hip_runtime.h>
#include <stdint.h>

#define D_DIM 512
#define NSTEPS 10
#define ALPHA0 0.1f
#define DT_C 0.1f
#define BETA_C 2.8982753492378875f

typedef __attribute__((ext_vector_type(8))) short short8;
typedef __attribute__((ext_vector_type(4))) float floatx4;
typedef __attribute__((ext_vector_type(4))) unsigned short ushortx4;
typedef unsigned int u32;

__device__ __forceinline__ unsigned short f32_to_bf16(float f) {
    union { float f; uint32_t u; } v;
    v.f = f;
    uint32_t u = v.u;
    return (unsigned short)((u + 0x7FFFu + ((u >> 16) & 1u)) >> 16);
}

__device__ __forceinline__ void async_load16(u32* lds, const u32* g) {
    __builtin_amdgcn_global_load_lds((const __attribute__((address_space(1))) u32*)g,
                                     (__attribute__((address_space(3))) u32*)lds, 16, 0, 0);
}

// ---------------------------------------------------------------------------
// Kernel 1: build L_rw in bf16 (row-major [e][d]). One wave per row.
// ---------------------------------------------------------------------------
__global__ __launch_bounds__(64) void prep_kernel(
    const float* __restrict__ W,
    unsigned short* __restrict__ Lbf)
{
    const int e = blockIdx.x;
    const int lane = threadIdx.x;
    const float* w = W + (size_t)e * D_DIM + lane * 8;
    const float4 v0 = *(const float4*)w;
    const float4 v1 = *(const float4*)(w + 4);
    float a[8] = { fabsf(v0.x), fabsf(v0.y), fabsf(v0.z), fabsf(v0.w),
                   fabsf(v1.x), fabsf(v1.y), fabsf(v1.z), fabsf(v1.w) };
    float s = a[0] + a[1] + a[2] + a[3] + a[4] + a[5] + a[6] + a[7];
#pragma unroll
    for (int off = 1; off < 64; off <<= 1) s += __shfl_xor(s, off, 64);
    const float inv = 1.0f / fmaxf(s, 1e-8f);
    short8 pk;
#pragma unroll
    for (int j = 0; j < 8; ++j) {
        const float diag = ((lane * 8 + j) == e) ? 1.0f : 0.0f;
        pk[j] = (short)f32_to_bf16(diag - a[j] * inv);
    }
    *(short8*)(Lbf + (size_t)e * D_DIM + lane * 8) = pk;
}

// ---------------------------------------------------------------------------
// Kernel 2: full 10-step settle + G build, ONE launch, 32 blocks x 1024 thr.
// Block owns 16 c-columns; wave w owns e-rows [32w, 32w+32) (2 m-frags).
// L partition per wave (round-5 proven, ushort* indexing):
//   m0 rows, all 16 kk : 64 VGPRs (Mreg)      <- needs the 128-VGPR budget
//   m1 rows, kk=0..6   : 7 KB/wave LDS (M1l, 112 KB total)
//   m1 rows, kk=7..15  : streamed from L2 via 4-deep register ring
// A (bf16 [c][d] swizzled) double-buffered in LDS (32 KB), 1 barrier/step.
// __launch_bounds__(1024,4): 16 waves/block = 4 waves/EU -> 128 VGPR cap,
// so Mreg stays in registers (round-5 spill: VGPR=64, 17 MB scratch writes).
// Epilogue: Gbf = g*A10 + (1-g)I, diag FOLDED IN (bf16).
// ---------------------------------------------------------------------------
__global__ __launch_bounds__(1024, 4) void chain_kernel(
    const unsigned short* __restrict__ Lbf,   // [e][d]
    const float* __restrict__ prec,
    const float* __restrict__ gate_alpha,
    unsigned short* __restrict__ Gbf)         // [e][d], diag folded
{
    const int tid = threadIdx.x;
    const int wave = tid >> 6, lane = tid & 63;
    const int lrow = lane & 15, q = lane >> 4;
    const int c_glob = blockIdx.x * 16 + lrow;
    const int ebase = wave * 32;

    __shared__ unsigned short Abuf[2][16 * D_DIM];   // 2 x 16 KiB, swizzled
    __shared__ unsigned short M1l[16 * 7 * 512];     // 112 KiB (ushort idx!)
    char* lds0 = (char*)Abuf[0];
    char* lds1 = (char*)Abuf[1];

    const short8* L0 = (const short8*)(Lbf + (size_t)(ebase + lrow) * D_DIM);
    const short8* L1 = (const short8*)(Lbf + (size_t)(ebase + 16 + lrow) * D_DIM);

    // persist m0 frags in registers (64 VGPRs)
    short8 Mreg[16];
#pragma unroll
    for (int kk = 0; kk < 16; ++kk) Mreg[kk] = L0[kk * 4 + q];

    // persist m1 frags kk=0..6 in this wave's private LDS slice
    // (ushort arithmetic: slot stride 512 shorts = 1 KB, lane stride 8 shorts = 16 B)
#pragma unroll
    for (int k7 = 0; k7 < 7; ++k7) {
        short8 v = L1[k7 * 4 + q];
        *(short8*)(M1l + (size_t)(wave * 7 + k7) * 512 + lane * 8) = v;
    }

    // pr = ALPHA0 + precision[e]
    float pr[2][4];
#pragma unroll
    for (int m = 0; m < 2; ++m)
#pragma unroll
        for (int j = 0; j < 4; ++j)
            pr[m][j] = ALPHA0 + prec[ebase + m * 16 + q * 4 + j];

    floatx4 At[2], Bt[2];
#pragma unroll
    for (int m = 0; m < 2; ++m) {
#pragma unroll
        for (int j = 0; j < 4; ++j) {
            const int e = ebase + m * 16 + q * 4 + j;
            At[m][j] = (e == c_glob) ? 1.0f : 0.0f;
            Bt[m][j] = 0.0f;
        }
    }

    // init buffer 0 with A0 = I
#pragma unroll
    for (int m = 0; m < 2; ++m) {
        ushortx4 pk;
#pragma unroll
        for (int j = 0; j < 4; ++j) pk[j] = f32_to_bf16(At[m][j]);
        int byte = lrow * (D_DIM * 2) + (ebase + m * 16 + q * 4) * 2;
        byte ^= (lrow & 7) << 4;
        *(ushortx4*)(lds0 + byte) = pk;
    }
    __syncthreads();

    for (int step = 0; step < NSTEPS; ++step) {
        char* src = (step & 1) ? lds1 : lds0;
        // prime 4-deep prefetch ring with streamed m1 frags kk=7..10
        short8 pf[4];
#pragma unroll
        for (int i = 0; i < 4; ++i) pf[i] = L1[(7 + i) * 4 + q];

        floatx4 acc[2] = {};
#pragma unroll
        for (int kk = 0; kk < 16; ++kk) {
            int bbyte = lrow * (D_DIM * 2) + (kk * 32 + q * 8) * 2;
            bbyte ^= (lrow & 7) << 4;
            const short8 b = *(const short8*)(src + bbyte);
            short8 a1;
            if (kk < 7) {
                a1 = *(const short8*)(M1l + (size_t)(wave * 7 + kk) * 512 + lane * 8);
            } else {
                a1 = pf[(kk - 7) & 3];
                if (kk + 4 < 16) pf[(kk - 7) & 3] = L1[(kk + 4) * 4 + q];
            }
            acc[0] = __builtin_amdgcn_mfma_f32_16x16x32_bf16(Mreg[kk], b, acc[0], 0, 0, 0);
            acc[1] = __builtin_amdgcn_mfma_f32_16x16x32_bf16(a1, b, acc[1], 0, 0, 0);
        }
        // state update (f32)
#pragma unroll
        for (int m = 0; m < 2; ++m) {
#pragma unroll
            for (int j = 0; j < 4; ++j) {
                const int e = ebase + m * 16 + q * 4 + j;
                const float p2 = pr[m][j];                       // ALPHA0 + p
                const float tgt = (e == c_glob) ? (p2 - ALPHA0) : 0.0f;
                const float force = -acc[m][j] - p2 * At[m][j]
                                    + tgt - BETA_C * Bt[m][j];
                Bt[m][j] += DT_C * force;
                At[m][j] += DT_C * Bt[m][j];
            }
        }
        if (step < NSTEPS - 1) {
            char* dst = (step & 1) ? lds0 : lds1;
#pragma unroll
            for (int m = 0; m < 2; ++m) {
                ushortx4 pk;
#pragma unroll
                for (int j = 0; j < 4; ++j) pk[j] = f32_to_bf16(At[m][j]);
                int byte = lrow * (D_DIM * 2) + (ebase + m * 16 + q * 4) * 2;
                byte ^= (lrow & 7) << 4;
                *(ushortx4*)(dst + byte) = pk;
            }
            __syncthreads();
        }
    }

    // epilogue: G = g*A10 + (1-g)I, diag folded into bf16
    const float g = tanhf(gate_alpha[0]);
#pragma unroll
    for (int m = 0; m < 2; ++m) {
#pragma unroll
        for (int j = 0; j < 4; ++j) {
            const int e = ebase + m * 16 + q * 4 + j;
            float val = g * At[m][j];
            if (e == c_glob) val += (1.0f - g);
            Gbf[(size_t)e * D_DIM + c_glob] = f32_to_bf16(val);
        }
    }
}

// ---------------------------------------------------------------------------
// Kernel 3: out = Hbf @ G^T (diag already folded into G).
// 512 blocks x 256 thr (4 waves), 32-row tiles. Per-wave independent async
// pipeline, ZERO barriers:
//   - H-tile rows [r0,r0+32) in registers (bf16, 2 m-frags x 16 kk = 64 VGPR)
//   - Gbf streamed via global_load_lds into 64-e-row chunks, double-buffered
//     (2 x 64 KB LDS), counted s_waitcnt vmcnt(16) (never 0 in-loop).
//   - wave w stages AND reads only chunk rows [16w,16w+16) -> no cross-wave dep.
//   - XOR-swizzle via pre-swizzled GLOBAL source + swizzled LDS read (rule #21);
//     unswizzled would be a 16-way bank conflict (all rows bank-aligned at 1 KB).
// ---------------------------------------------------------------------------
__global__ __launch_bounds__(256) void out_gemm(
    const float* __restrict__ H,              // [16384][512]
    const unsigned short* __restrict__ Gbf,   // [e][d] bf16, diag folded
    float* __restrict__ Out)
{
    const int r0 = blockIdx.x * 32;
    const int tid = threadIdx.x;
    const int wave = tid >> 6, lane = tid & 63;
    const int lrow = lane & 15, q = lane >> 4;

    __shared__ unsigned short Gl[2][64 * D_DIM];   // 2 x 64 KiB

    // stage chunk 0 (rows [wave*16, wave*16+16) of e-chunk 0)
#pragma unroll
    for (int i = 0; i < 16; ++i) {
        const int rl = wave * 16 + i;
        const char* gsrc = (const char*)Gbf + (size_t)rl * 1024
                           + ((lane * 16) ^ ((rl & 7) << 4));
        async_load16((u32*)((char*)Gl[0] + rl * 1024), (const u32*)gsrc);
    }

    // H tile -> registers (bf16)
    short8 Hreg[2][16];
#pragma unroll
    for (int m = 0; m < 2; ++m) {
#pragma unroll
        for (int kk = 0; kk < 16; ++kk) {
            const float* hs = H + (size_t)(r0 + m * 16 + lrow) * D_DIM + kk * 32 + q * 8;
            const float4 v0 = *(const float4*)hs;
            const float4 v1 = *(const float4*)(hs + 4);
            short8 pk;
            pk[0] = (short)f32_to_bf16(v0.x); pk[1] = (short)f32_to_bf16(v0.y);
            pk[2] = (short)f32_to_bf16(v0.z); pk[3] = (short)f32_to_bf16(v0.w);
            pk[4] = (short)f32_to_bf16(v1.x); pk[5] = (short)f32_to_bf16(v1.y);
            pk[6] = (short)f32_to_bf16(v1.z); pk[7] = (short)f32_to_bf16(v1.w);
            Hreg[m][kk] = pk;
        }
    }
    __builtin_amdgcn_sched_barrier(0);

    const int R = wave * 16 + lrow;          // chunk-local row this lane reads

    for (int c = 0; c < 8; ++c) {
        char* gl = (char*)Gl[c & 1];
        if (c + 1 < 8) {
            char* gld = (char*)Gl[(c + 1) & 1];
#pragma unroll
            for (int i = 0; i < 16; ++i) {
                const int rl = wave * 16 + i;
                const char* gsrc = (const char*)Gbf + (size_t)((c + 1) * 64 + rl) * 1024
                                   + ((lane * 16) ^ ((rl & 7) << 4));
                async_load16((u32*)(gld + rl * 1024), (const u32*)gsrc);
            }
            asm volatile("s_waitcnt vmcnt(16)" ::: "memory");
        } else {
            asm volatile("s_waitcnt vmcnt(0)" ::: "memory");
        }
        __builtin_amdgcn_sched_barrier(0);

        floatx4 acc[2] = {};
#pragma unroll
        for (int kk = 0; kk < 16; ++kk) {
            int byte = R * 1024 + (((kk * 32 + q * 8) * 2) ^ ((R & 7) << 4));
            const short8 b = *(const short8*)(gl + byte);
            acc[0] = __builtin_amdgcn_mfma_f32_16x16x32_bf16(Hreg[0][kk], b, acc[0], 0, 0, 0);
            acc[1] = __builtin_amdgcn_mfma_f32_16x16x32_bf16(Hreg[1][kk], b, acc[1], 0, 0, 0);
        }
#pragma unroll
        for (int m = 0; m < 2; ++m)
#pragma unroll
            for (int j = 0; j < 4; ++j)
                Out[(size_t)(r0 + m * 16 + q * 4 + j) * D_DIM + c * 64 + R] = acc[m][j];
    }
}

// ---------------------------------------------------------------------------
extern "C" void kernel_launch(void* const* d_in, const int* in_sizes, int n_in,
                              void* d_out, int out_size, void* d_ws, size_t ws_size,
                              hipStream_t stream)
{
    const float* H    = (const float*)d_in[0];   // (4,4096,512)
    const float* W    = (const float*)d_in[1];   // (512,512)
    const float* gate = (const float*)d_in[2];   // (1,)
    const float* prec = (const float*)d_in[3];   // (512,)
    float* out = (float*)d_out;
    char* ws = (char*)d_ws;

    unsigned short* Lbf = (unsigned short*)(ws);                 // 512 KiB
    unsigned short* Gbf = (unsigned short*)(ws + (512u << 10));  // 512 KiB

    prep_kernel<<<dim3(D_DIM), dim3(64), 0, stream>>>(W, Lbf);

    chain_kernel<<<dim3(D_DIM / 16), dim3(1024), 0, stream>>>(
        Lbf, prec, gate, Gbf);

    out_gemm<<<dim3(16384 / 32), dim3(256), 0, stream>>>(H, Gbf, out);
}